// Round 12
// baseline (83.860 us; speedup 1.0000x reference)
//
#include <hip/hip_runtime.h>

typedef _Float16 f16;
typedef _Float16 half8 __attribute__((ext_vector_type(8)));
typedef _Float16 f16x2 __attribute__((ext_vector_type(2)));
typedef _Float16 f16x4 __attribute__((ext_vector_type(4)));
typedef float    f32x4 __attribute__((ext_vector_type(4)));

#define DM    768
#define QD    96
#define MFMA16(a,b,c) __builtin_amdgcn_mfma_f32_16x16x32_f16(a, b, c, 0, 0, 0)

// ---------------------------------------------------------------------------
__device__ __forceinline__ void async_copy16(const f16* g, f16* l) {
  __builtin_amdgcn_global_load_lds((const __attribute__((address_space(1))) void*)g,
                                   (__attribute__((address_space(3))) void*)l,
                                   16, 0, 0);
}

// ---------------------------------------------------------------------------
// merged prep: x cast (b<3072), weight cast/pad (b<4420), sincos table (rest)
// ---------------------------------------------------------------------------
__global__ __launch_bounds__(256) void prep_kernel(const float* __restrict__ x,
                                                   const float* __restrict__ Wqkv,
                                                   const float* __restrict__ bqkv,
                                                   const float* __restrict__ Wout,
                                                   f16* __restrict__ xh,
                                                   f16* __restrict__ w1h,
                                                   f16* __restrict__ w2h,
                                                   float* __restrict__ b1p,
                                                   float* __restrict__ ctab,
                                                   float* __restrict__ stab) {
  const int NW1 = 1024 * 768 / 4;
  const int NW2 = 768 * 768 / 4;
  int b = blockIdx.x;
  if (b < 3072) {                       // x cast: 4096*768/4 items
    int idx = b * 256 + threadIdx.x;
    f32x4 v = ((const f32x4*)x)[idx];
    f16x4 o;
    o[0] = (f16)v[0]; o[1] = (f16)v[1]; o[2] = (f16)v[2]; o[3] = (f16)v[3];
    ((f16x4*)xh)[idx] = o;
    return;
  }
  if (b < 4420) {                       // weights + bias
    int idx = (b - 3072) * 256 + threadIdx.x;
    if (idx < NW1) {
      int r = idx / 192;
      f16x4 o;
      if (r < 960) {
        f32x4 v = ((const f32x4*)Wqkv)[idx];
        o[0] = (f16)v[0]; o[1] = (f16)v[1]; o[2] = (f16)v[2]; o[3] = (f16)v[3];
      } else {
        o[0] = (f16)0.f; o[1] = (f16)0.f; o[2] = (f16)0.f; o[3] = (f16)0.f;
      }
      ((f16x4*)w1h)[idx] = o;
    } else if (idx < NW1 + NW2) {
      int j = idx - NW1;
      f32x4 v = ((const f32x4*)Wout)[j];
      f16x4 o;
      o[0] = (f16)v[0]; o[1] = (f16)v[1]; o[2] = (f16)v[2]; o[3] = (f16)v[3];
      ((f16x4*)w2h)[j] = o;
    } else {
      int j = idx - (NW1 + NW2);
      b1p[j] = (j < 960) ? bqkv[j] : 0.f;
    }
    return;
  }
  // sincos table: 4096 pos x 48 freqs (padded loop to 64, pow2 math)
  int idx = (b - 4420) * 256 + threadIdx.x;
  int pos = idx >> 6, f = idx & 63;
  if (f < 48) {
    float theta = exp2f((float)f * -0.27682734f);   // 10000^(-2f/96)
    float s, c;
    sincosf((float)pos * theta, &s, &c);
    ctab[pos * 48 + f] = c;
    stab[pos * 48 + f] = s;
  }
}

// ---------------------------------------------------------------------------
// shared GEMM macros: 32x128 tile, 4 waves (each 32x32 out), BK=64.
// A-fragments load DIRECTLY global->VGPR (L2-hot; A-broadcast redundancy
// and half the LDS read traffic eliminated), double-buffered one step ahead.
// B via LDS, double-buffered (32 KB). Counted vmcnt: per step issue order is
// Aload(t+1) then Bstage(t+2) -> top-of-step vmcnt(4) leaves only B(t+2)
// outstanding (A(t), B(t), A(t+1)... wait A(t) needed: A(t) issued 1 step
// ago followed by 4 B + nothing -> drained at vmcnt(4)). Last step vmcnt(0).
// LDS linear [row][64] halves; B k-chunk XOR-swizzled (chunk ^ (row&7)) on
// BOTH staging source and ds_read address (rule #21).
// ---------------------------------------------------------------------------
#define GEMM_VM4  asm volatile("s_waitcnt vmcnt(4)" ::: "memory")
#define GEMM_VM0  asm volatile("s_waitcnt vmcnt(0)" ::: "memory")
#define GEMM_SB   __builtin_amdgcn_s_barrier()
#define GEMM_SCB  __builtin_amdgcn_sched_barrier(0)

#define GEMM_STAGE_B(BUF, K0)                                       \
  do {                                                              \
    async_copy16(Bp + (K0),           lB0 + (BUF) * 8192);          \
    async_copy16(Bp + 32 * K + (K0),  lB0 + (BUF) * 8192 + 2048);   \
    async_copy16(Bp + 64 * K + (K0),  lB0 + (BUF) * 8192 + 4096);   \
    async_copy16(Bp + 96 * K + (K0),  lB0 + (BUF) * 8192 + 6144);   \
  } while (0)

#define GEMM_LOAD_A(REG, K0)                                        \
  do {                                                              \
    _Pragma("unroll")                                               \
    for (int m = 0; m < 2; ++m)                                     \
      _Pragma("unroll")                                             \
      for (int kk = 0; kk < 2; ++kk)                                \
        REG[m][kk] = *(const half8*)(Aq + (size_t)(m * 16) * K +    \
                                     (K0) + (((kk << 2) | kg) << 3)); \
  } while (0)

#define GEMM_COMPUTE(BUF, AREG)                                                \
  do {                                                                         \
    half8 b[2][2];                                                             \
    _Pragma("unroll")                                                          \
    for (int n = 0; n < 2; ++n) {                                              \
      int row = w * 32 + n * 16 + fr;                                          \
      _Pragma("unroll")                                                        \
      for (int kk = 0; kk < 2; ++kk) {                                         \
        int c = (kk << 2) | kg;                                                \
        b[n][kk] = *(const half8*)&Bs[BUF][row * 64 + ((c ^ (row & 7)) << 3)]; \
      }                                                                        \
    }                                                                          \
    _Pragma("unroll")                                                          \
    for (int m = 0; m < 2; ++m)                                                \
      _Pragma("unroll")                                                        \
      for (int n = 0; n < 2; ++n) {                                            \
        acc[m][n] = MFMA16(AREG[m][0], b[n][0], acc[m][n]);                    \
        acc[m][n] = MFMA16(AREG[m][1], b[n][1], acc[m][n]);                    \
      }                                                                        \
  } while (0)

#define GEMM_PROLOGUE_AND_LOOP                                      \
  __shared__ f16 Bs[2][128 * 64];                                   \
  const int t  = threadIdx.x;                                       \
  const int bm = blockIdx.x * 32;                                   \
  const int bn = blockIdx.y * 128;                                  \
  const int w  = t >> 6, l = t & 63;                                \
  const int fr = l & 15, kg = l >> 4;                               \
  f32x4 acc[2][2] = {};                                             \
  const int srow = t >> 3;                                          \
  const int skc  = ((t & 7) ^ (srow & 7)) << 3;  /* swizzled src k */ \
  const f16* Bp = B + (size_t)(bn + srow) * K + skc;                \
  const f16* Aq = A + (size_t)(bm + fr) * K;                        \
  f16* lB0 = &Bs[0][t * 8];                                         \
  const int nt = K >> 6; /* even, >= 4 */                           \
  half8 a0[2][2], a1[2][2];                                         \
  GEMM_STAGE_B(0, 0);                                               \
  GEMM_LOAD_A(a0, 0);                                               \
  GEMM_STAGE_B(1, 64);                                              \
  for (int tk = 0; tk < nt; ++tk) {                                 \
    if (tk + 1 < nt) { GEMM_VM4; } else { GEMM_VM0; }               \
    GEMM_SB; GEMM_SCB;                                              \
    if (tk & 1) { GEMM_COMPUTE(1, a1); } else { GEMM_COMPUTE(0, a0); } \
    GEMM_SCB; GEMM_SB;                                              \
    if (tk + 1 < nt) {                                              \
      if (tk & 1) { GEMM_LOAD_A(a0, (tk + 1) << 6); }               \
      else        { GEMM_LOAD_A(a1, (tk + 1) << 6); }               \
    }                                                               \
    if (tk + 2 < nt) GEMM_STAGE_B(tk & 1, (tk + 2) << 6);           \
  }

// ---------------------------------------------------------------------------
// GEMM2: C[M x ldc](f32) = A * B^T + bias; grid = (M/32, N/128)
// ---------------------------------------------------------------------------
__global__ __launch_bounds__(256) void gemm_f16_tn(const f16* __restrict__ A,
                                                   const f16* __restrict__ B,
                                                   const float* __restrict__ bias,
                                                   float* __restrict__ C,
                                                   int K, int ldc) {
  GEMM_PROLOGUE_AND_LOOP
  const int r0 = kg * 4;
#pragma unroll
  for (int n = 0; n < 2; ++n) {
    int col = bn + w * 32 + n * 16 + fr;
    float bv = bias[col];
#pragma unroll
    for (int m = 0; m < 2; ++m) {
      int row = bm + m * 16 + r0;
#pragma unroll
      for (int r = 0; r < 4; ++r)
        C[(size_t)(row + r) * ldc + col] = acc[m][n][r] + bv;
    }
  }
}

// ---------------------------------------------------------------------------
// GEMM1 fused: qkv GEMM + bias + RoPE (table) + f16 hi/lo split + V transpose.
// Columns: [0,96)=k -> kh/kl; [96,192)=v -> vT (LDS transpose in Bs[0],
// coalesced stores); [192,960)=q -> qh/ql; >=960 pad (skipped).
// grid = (M/32, 8). RoPE pair (2f,2f+1): even lane computes BOTH outputs
// (bit-identical) -> paired f16x2 stores.
// ---------------------------------------------------------------------------
__global__ __launch_bounds__(256) void gemm_qkv_rope(const f16* __restrict__ A,
                                                     const f16* __restrict__ B,
                                                     const float* __restrict__ bias,
                                                     const float* __restrict__ ctab,
                                                     const float* __restrict__ stab,
                                                     f16* __restrict__ qh,
                                                     f16* __restrict__ ql,
                                                     f16* __restrict__ kh,
                                                     f16* __restrict__ kl,
                                                     f16* __restrict__ vT) {
  const int K = 768;
  GEMM_PROLOGUE_AND_LOOP
  const int r0 = kg * 4;
  // v-column transpose scratch overlaid on Bs[0] (last compute reads Bs[1],
  // and a barrier separates). stride 40 halves; 64 cols x 32 rows = 5 KB.
  f16* ls = &Bs[0][0];
  const int vlo = (bn < 96) ? 96 : bn;
  const int vhi = (bn + 128 < 192) ? (bn + 128) : 192;
  const bool has_v = vlo < vhi;                 // blocks y=0 (32 cols), y=1 (64)
  const bool even = !(fr & 1);
#pragma unroll
  for (int n = 0; n < 2; ++n) {
    int col = bn + w * 32 + n * 16 + fr;
    float bv = bias[col];
    int seg = (col * 683) >> 16;        // col / 96
    int f = (col - seg * 96) >> 1;
#pragma unroll
    for (int m = 0; m < 2; ++m) {
      int row = bm + m * 16 + r0;
      if (seg == 1) {                   // v column: pack 4 rows -> LDS
        f16x4 pk;
#pragma unroll
        for (int r = 0; r < 4; ++r) pk[r] = (f16)(acc[m][n][r] + bv);
        *(f16x4*)&ls[(col - vlo) * 40 + m * 16 + r0] = pk;
        continue;
      }
#pragma unroll
      for (int r = 0; r < 4; ++r) {
        float v = acc[m][n][r] + bv;
        float p = __shfl_xor(v, 1);     // partner column of the rope pair
        if (even && col < 960) {        // lane owns the (even,odd) pair
          float c = ctab[(row + r) * 48 + f];
          float s = stab[(row + r) * 48 + f];
          float re = v * c - p * s;
          float ro = v * s + p * c;
          f16 hie = (f16)re, hio = (f16)ro;
          f16x2 hv; hv[0] = hie; hv[1] = hio;
          f16x2 lv; lv[0] = (f16)(re - (float)hie); lv[1] = (f16)(ro - (float)hio);
          if (seg == 0) {
            *(f16x2*)(kh + (size_t)(row + r) * QD + col) = hv;
            *(f16x2*)(kl + (size_t)(row + r) * QD + col) = lv;
          } else {
            int qc = col - 192;
            *(f16x2*)(qh + (size_t)(row + r) * DM + qc) = hv;
            *(f16x2*)(ql + (size_t)(row + r) * DM + qc) = lv;
          }
        }
      }
    }
  }
  if (has_v) {                          // coalesced vT write-out
    __syncthreads();
    const int nv = vhi - vlo;           // 32 or 64
    for (int idx = t; idx < nv * 4; idx += 256) {
      int cl = idx >> 2, sg = idx & 3;
      *(half8*)(vT + (size_t)(vlo - 96 + cl) * 4096 + bm + sg * 8) =
          *(half8*)&ls[cl * 40 + sg * 8];
    }
  }
}

// ---------------------------------------------------------------------------
// MFMA windowed attention (unchanged from round 9).
// ---------------------------------------------------------------------------
__global__ __launch_bounds__(256) void attn2_kernel(const f16* __restrict__ qh,
                                                    const f16* __restrict__ ql,
                                                    const f16* __restrict__ kh,
                                                    const f16* __restrict__ kl,
                                                    const f16* __restrict__ vT,
                                                    f16* __restrict__ aout) {
  __shared__ f16 kbuf[192 * 104];      // K_hi tile
  __shared__ f16 klbuf[192 * 104];     // K_lo tile
  __shared__ f16 vbuf[96 * 200];       // vT tile [96][200]
  __shared__ f16 pbuf[4][32 * 40];     // per-wave P chunk (wave-private)
  const int t  = threadIdx.x, w = t >> 6, l = t & 63;
  const int fr = l & 15, kg = l >> 4;
  const int i0 = blockIdx.x * 64;
  const int h  = blockIdx.y * 2 + (w >> 1);
  const int q0 = (w & 1) * 32;
  const int jbase = i0 - 128;
  const int nlo = (w & 1) ? 2 : 0;     // live key-chunks: [nlo, nlo+10)

  // stage K_hi + K_lo tiles (192 x 96 -> padded 104), coalesced
  for (int it = 0; it < 9; ++it) {
    int c = t + 256 * it;
    int row = c / 12, seg = c - row * 12;
    int jabs = jbase + row; if (jabs < 0) jabs = 0;
    *(half8*)(kbuf + row * 104 + seg * 8) =
        *(const half8*)(kh + (size_t)jabs * QD + seg * 8);
    *(half8*)(klbuf + row * 104 + seg * 8) =
        *(const half8*)(kl + (size_t)jabs * QD + seg * 8);
  }
  // stage vT tile (96 x 192 -> padded 200), coalesced
  for (int it = 0; it < 9; ++it) {
    int c = t + 256 * it;
    int row = c / 24, seg = c - row * 24;
    int col0 = jbase + seg * 8; if (col0 < 0) col0 = 0;
    *(half8*)(vbuf + row * 200 + seg * 8) =
        *(const half8*)(vT + (size_t)row * 4096 + col0);
  }

  half8 a_h[2][3], a_l[2][3];
#pragma unroll
  for (int m = 0; m < 2; ++m) {
    size_t qoff = (size_t)(i0 + q0 + m * 16 + fr) * DM + h * QD;
#pragma unroll
    for (int kc = 0; kc < 3; ++kc) {
      a_h[m][kc] = *(const half8*)(qh + qoff + kc * 32 + kg * 8);
      a_l[m][kc] = *(const half8*)(ql + qoff + kc * 32 + kg * 8);
    }
  }
  __syncthreads();

  // S = Q K^T  (hi*hi + lo*hi + hi*lo)
  f32x4 s[2][12];
#pragma unroll
  for (int m = 0; m < 2; ++m)
#pragma unroll
    for (int n = 0; n < 12; ++n)
      s[m][n] = (f32x4){0.f, 0.f, 0.f, 0.f};

  __builtin_amdgcn_s_setprio(1);
#pragma unroll
  for (int n = 0; n < 12; ++n) {
    if (n < nlo || n >= nlo + 10) continue;
    int krow = n * 16 + fr;
#pragma unroll
    for (int kc = 0; kc < 3; ++kc) {
      half8 b_h = *(const half8*)(kbuf + krow * 104 + kc * 32 + kg * 8);
      half8 b_l = *(const half8*)(klbuf + krow * 104 + kc * 32 + kg * 8);
      s[0][n] = MFMA16(a_h[0][kc], b_h, s[0][n]);
      s[1][n] = MFMA16(a_h[1][kc], b_h, s[1][n]);
      s[0][n] = MFMA16(a_l[0][kc], b_h, s[0][n]);
      s[1][n] = MFMA16(a_l[1][kc], b_h, s[1][n]);
      s[0][n] = MFMA16(a_h[0][kc], b_l, s[0][n]);
      s[1][n] = MFMA16(a_h[1][kc], b_l, s[1][n]);
    }
  }
  __builtin_amdgcn_s_setprio(0);

  // mask + scale + softmax
  const int jmin = (i0 < 128) ? (128 - i0) : 0;
  const float scale = 9.79795897113271f;
  float mx[2][4], sm[2][4], inv[2][4];
#pragma unroll
  for (int m = 0; m < 2; ++m)
#pragma unroll
    for (int r = 0; r < 4; ++r) mx[m][r] = -1e30f;

#pragma unroll
  for (int m = 0; m < 2; ++m)
#pragma unroll
    for (int n = 0; n < 12; ++n) {
      if (n < nlo || n >= nlo + 10) continue;
      int jloc = n * 16 + fr;
#pragma unroll
      for (int r = 0; r < 4; ++r) {
        int iloc = q0 + m * 16 + kg * 4 + r;
        bool valid = (jloc > iloc) && (jloc <= iloc + 128) && (jloc >= jmin);
        float v = valid ? s[m][n][r] * scale : -1e30f;
        s[m][n][r] = v;
        mx[m][r] = fmaxf(mx[m][r], v);
      }
    }
#pragma unroll
  for (int m = 0; m < 2; ++m)
#pragma unroll
    for (int r = 0; r < 4; ++r) {
      float v = mx[m][r];
      v = fmaxf(v, __shfl_xor(v, 1));
      v = fmaxf(v, __shfl_xor(v, 2));
      v = fmaxf(v, __shfl_xor(v, 4));
      v = fmaxf(v, __shfl_xor(v, 8));
      mx[m][r] = v;
      sm[m][r] = 0.f;
    }
#pragma unroll
  for (int m = 0; m < 2; ++m)
#pragma unroll
    for (int n = 0; n < 12; ++n) {
      if (n < nlo || n >= nlo + 10) continue;
#pragma unroll
      for (int r = 0; r < 4; ++r) {
        float p = __expf(s[m][n][r] - mx[m][r]);
        s[m][n][r] = p;
        sm[m][r] += p;
      }
    }
#pragma unroll
  for (int m = 0; m < 2; ++m)
#pragma unroll
    for (int r = 0; r < 4; ++r) {
      float v = sm[m][r];
      v += __shfl_xor(v, 1);
      v += __shfl_xor(v, 2);
      v += __shfl_xor(v, 4);
      v += __shfl_xor(v, 8);
      inv[m][r] = 1.f / v;
    }

  // PV over live key-chunks (pbuf wave-private: same-wave DS ordering, no barriers)
  f16* pw = pbuf[w];
  const int c6lo = nlo >> 1;           // 5 of 6 chunks live
  f32x4 o[2][6];
#pragma unroll
  for (int m = 0; m < 2; ++m)
#pragma unroll
    for (int dn = 0; dn < 6; ++dn)
      o[m][dn] = (f32x4){0.f, 0.f, 0.f, 0.f};

#pragma unroll
  for (int c6 = 0; c6 < 6; ++c6) {
    if (c6 < c6lo || c6 >= c6lo + 5) continue;
#pragma unroll
    for (int m = 0; m < 2; ++m)
#pragma unroll
      for (int nn = 0; nn < 2; ++nn)
#pragma unroll
        for (int r = 0; r < 4; ++r)
          pw[(m * 16 + kg * 4 + r) * 40 + nn * 16 + fr] = (f16)s[m][2 * c6 + nn][r];
    half8 ap0 = *(half8*)(pw + fr * 40 + kg * 8);
    half8 ap1 = *(half8*)(pw + (16 + fr) * 40 + kg * 8);
    __builtin_amdgcn_s_setprio(1);
#pragma unroll
    for (int dn = 0; dn < 6; ++dn) {
      half8 bv = *(half8*)(vbuf + (dn * 16 + fr) * 200 + c6 * 32 + kg * 8);
      o[0][dn] = MFMA16(ap0, bv, o[0][dn]);
      o[1][dn] = MFMA16(ap1, bv, o[1][dn]);
    }
    __builtin_amdgcn_s_setprio(0);
  }

#pragma unroll
  for (int m = 0; m < 2; ++m)
#pragma unroll
    for (int dn = 0; dn < 6; ++dn) {
      int col = h * QD + dn * 16 + fr;
#pragma unroll
      for (int r = 0; r < 4; ++r) {
        int row = i0 + q0 + m * 16 + kg * 4 + r;
        aout[(size_t)row * DM + col] = (f16)(o[m][dn][r] * inv[m][r]);
      }
    }
}

// ---------------------------------------------------------------------------
extern "C" void kernel_launch(void* const* d_in, const int* in_sizes, int n_in,
                              void* d_out, int out_size, void* d_ws, size_t ws_size,
                              hipStream_t stream) {
  const float* x    = (const float*)d_in[0];
  const float* Wqkv = (const float*)d_in[1];
  const float* bqkv = (const float*)d_in[2];
  const float* Wout = (const float*)d_in[3];
  const float* bout = (const float*)d_in[4];
  float* out = (float*)d_out;

  char* ws = (char*)d_ws;
  f16*   xh   = (f16*)(ws);                    // 6291456
  f16*   w1h  = (f16*)(ws + 6291456);          // 1572864
  f16*   w2h  = (f16*)(ws + 7864320);          // 1179648
  float* b1p  = (float*)(ws + 9043968);        // 4096
  float* ctab = (float*)(ws + 9048064);        // 786432
  float* stab = (float*)(ws + 9834496);        // 786432
  f16*   qh   = (f16*)(ws + 10620928);         // 6291456
  f16*   ql   = (f16*)(ws + 16912384);         // 6291456
  f16*   kh   = (f16*)(ws + 23203840);         // 786432
  f16*   kl   = (f16*)(ws + 23990272);         // 786432
  f16*   vT   = (f16*)(ws + 24776704);         // 786432
  f16*   aout = (f16*)(ws + 25563136);         // 6291456 -> total 31854592

  prep_kernel<<<dim3(5444), dim3(256), 0, stream>>>(x, Wqkv, bqkv, Wout,
                                                    xh, w1h, w2h, b1p, ctab, stab);
  gemm_qkv_rope<<<dim3(128, 8), dim3(256), 0, stream>>>(xh, w1h, b1p, ctab, stab,
                                                        qh, ql, kh, kl, vT);
  attn2_kernel<<<dim3(64, 4), dim3(256), 0, stream>>>(qh, ql, kh, kl, vT, aout);
  gemm_f16_tn<<<dim3(128, 6), dim3(256), 0, stream>>>(aout, w2h, bout, out, 768, 768);
}

// Round 13
// 57.283 us; speedup vs baseline: 1.4640x; 1.4640x over previous
//
#include <hip/hip_runtime.h>

typedef _Float16 f16;
typedef _Float16 half8 __attribute__((ext_vector_type(8)));
typedef _Float16 f16x2 __attribute__((ext_vector_type(2)));
typedef _Float16 f16x4 __attribute__((ext_vector_type(4)));
typedef float    f32x4 __attribute__((ext_vector_type(4)));

#define DM    768
#define QD    96
#define MFMA16(a,b,c) __builtin_amdgcn_mfma_f32_16x16x32_f16(a, b, c, 0, 0, 0)

// ---------------------------------------------------------------------------
__device__ __forceinline__ void async_copy16(const f16* g, f16* l) {
  __builtin_amdgcn_global_load_lds((const __attribute__((address_space(1))) void*)g,
                                   (__attribute__((address_space(3))) void*)l,
                                   16, 0, 0);
}

// ---------------------------------------------------------------------------
// merged prep: x cast (b<3072), weight cast/pad (b<4420), sincos table (rest)
// ---------------------------------------------------------------------------
__global__ __launch_bounds__(256) void prep_kernel(const float* __restrict__ x,
                                                   const float* __restrict__ Wqkv,
                                                   const float* __restrict__ bqkv,
                                                   const float* __restrict__ Wout,
                                                   f16* __restrict__ xh,
                                                   f16* __restrict__ w1h,
                                                   f16* __restrict__ w2h,
                                                   float* __restrict__ b1p,
                                                   float* __restrict__ ctab,
                                                   float* __restrict__ stab) {
  const int NW1 = 1024 * 768 / 4;
  const int NW2 = 768 * 768 / 4;
  int b = blockIdx.x;
  if (b < 3072) {                       // x cast: 4096*768/4 items
    int idx = b * 256 + threadIdx.x;
    f32x4 v = ((const f32x4*)x)[idx];
    f16x4 o;
    o[0] = (f16)v[0]; o[1] = (f16)v[1]; o[2] = (f16)v[2]; o[3] = (f16)v[3];
    ((f16x4*)xh)[idx] = o;
    return;
  }
  if (b < 4420) {                       // weights + bias
    int idx = (b - 3072) * 256 + threadIdx.x;
    if (idx < NW1) {
      int r = idx / 192;
      f16x4 o;
      if (r < 960) {
        f32x4 v = ((const f32x4*)Wqkv)[idx];
        o[0] = (f16)v[0]; o[1] = (f16)v[1]; o[2] = (f16)v[2]; o[3] = (f16)v[3];
      } else {
        o[0] = (f16)0.f; o[1] = (f16)0.f; o[2] = (f16)0.f; o[3] = (f16)0.f;
      }
      ((f16x4*)w1h)[idx] = o;
    } else if (idx < NW1 + NW2) {
      int j = idx - NW1;
      f32x4 v = ((const f32x4*)Wout)[j];
      f16x4 o;
      o[0] = (f16)v[0]; o[1] = (f16)v[1]; o[2] = (f16)v[2]; o[3] = (f16)v[3];
      ((f16x4*)w2h)[j] = o;
    } else {
      int j = idx - (NW1 + NW2);
      b1p[j] = (j < 960) ? bqkv[j] : 0.f;
    }
    return;
  }
  // sincos table: 4096 pos x 48 freqs (padded loop to 64, pow2 math)
  int idx = (b - 4420) * 256 + threadIdx.x;
  int pos = idx >> 6, f = idx & 63;
  if (f < 48) {
    float theta = exp2f((float)f * -0.27682734f);   // 10000^(-2f/96)
    float s, c;
    sincosf((float)pos * theta, &s, &c);
    ctab[pos * 48 + f] = c;
    stab[pos * 48 + f] = s;
  }
}

// ---------------------------------------------------------------------------
// shared GEMM macros (REVERTED to round-11 structure, the 54.9 best):
// 32x128 tile, 4 waves (each 32x32 out), BK=64, double-buffered LDS
// (40 KB -> 4 blocks/CU = 16 waves/CU), counted-vmcnt pipeline.
// LDS linear [row][64] halves; k-chunk XOR-swizzled (chunk ^ (row&7)) on
// BOTH staging source and ds_read address (rule #21).
// ---------------------------------------------------------------------------
#define GEMM_VM5  asm volatile("s_waitcnt vmcnt(5)" ::: "memory")
#define GEMM_VM0  asm volatile("s_waitcnt vmcnt(0)" ::: "memory")
#define GEMM_SB   __builtin_amdgcn_s_barrier()
#define GEMM_SCB  __builtin_amdgcn_sched_barrier(0)

#define GEMM_STAGE(BUF, K0)                                         \
  do {                                                              \
    async_copy16(Ap + (K0),           lA0 + (BUF) * 2048);          \
    async_copy16(Bp + (K0),           lB0 + (BUF) * 8192);          \
    async_copy16(Bp + 32 * K + (K0),  lB0 + (BUF) * 8192 + 2048);   \
    async_copy16(Bp + 64 * K + (K0),  lB0 + (BUF) * 8192 + 4096);   \
    async_copy16(Bp + 96 * K + (K0),  lB0 + (BUF) * 8192 + 6144);   \
  } while (0)

#define GEMM_COMPUTE(BUF)                                                      \
  do {                                                                         \
    half8 a[2][2], b[2][2];                                                    \
    _Pragma("unroll")                                                          \
    for (int m = 0; m < 2; ++m) {                                              \
      int row = m * 16 + fr;                                                   \
      _Pragma("unroll")                                                        \
      for (int kk = 0; kk < 2; ++kk) {                                         \
        int c = (kk << 2) | kg;                                                \
        a[m][kk] = *(const half8*)&As[BUF][row * 64 + ((c ^ (row & 7)) << 3)]; \
      }                                                                        \
    }                                                                          \
    _Pragma("unroll")                                                          \
    for (int n = 0; n < 2; ++n) {                                              \
      int row = w * 32 + n * 16 + fr;                                          \
      _Pragma("unroll")                                                        \
      for (int kk = 0; kk < 2; ++kk) {                                         \
        int c = (kk << 2) | kg;                                                \
        b[n][kk] = *(const half8*)&Bs[BUF][row * 64 + ((c ^ (row & 7)) << 3)]; \
      }                                                                        \
    }                                                                          \
    _Pragma("unroll")                                                          \
    for (int m = 0; m < 2; ++m)                                                \
      _Pragma("unroll")                                                        \
      for (int n = 0; n < 2; ++n) {                                            \
        acc[m][n] = MFMA16(a[m][0], b[n][0], acc[m][n]);                       \
        acc[m][n] = MFMA16(a[m][1], b[n][1], acc[m][n]);                       \
      }                                                                        \
  } while (0)

#define GEMM_PROLOGUE_AND_LOOP                                      \
  __shared__ f16 As[2][32 * 64];                                    \
  __shared__ f16 Bs[2][128 * 64];                                   \
  const int t  = threadIdx.x;                                       \
  const int bm = blockIdx.x * 32;                                   \
  const int bn = blockIdx.y * 128;                                  \
  const int w  = t >> 6, l = t & 63;                                \
  const int fr = l & 15, kg = l >> 4;                               \
  f32x4 acc[2][2] = {};                                             \
  const int srow = t >> 3;                                          \
  const int skc  = ((t & 7) ^ (srow & 7)) << 3;  /* swizzled src k */ \
  const f16* Ap = A + (size_t)(bm + srow) * K + skc;                \
  const f16* Bp = B + (size_t)(bn + srow) * K + skc;                \
  f16* lA0 = &As[0][t * 8];                                         \
  f16* lB0 = &Bs[0][t * 8];                                         \
  const int nt = K >> 6; /* >= 3 */                                 \
  GEMM_STAGE(0, 0);                                                 \
  GEMM_STAGE(1, 64);                                                \
  for (int tk = 0; tk < nt; ++tk) {                                 \
    if (tk + 1 < nt) { GEMM_VM5; } else { GEMM_VM0; }               \
    GEMM_SB; GEMM_SCB;                                              \
    GEMM_COMPUTE(tk & 1);                                           \
    GEMM_SCB; GEMM_SB;                                              \
    if (tk + 2 < nt) GEMM_STAGE(tk & 1, (tk + 2) << 6);             \
  }

// ---------------------------------------------------------------------------
// GEMM2: C[M x ldc](f32) = A * B^T + bias; grid = (M/32, N/128)
// ---------------------------------------------------------------------------
__global__ __launch_bounds__(256) void gemm_f16_tn(const f16* __restrict__ A,
                                                   const f16* __restrict__ B,
                                                   const float* __restrict__ bias,
                                                   float* __restrict__ C,
                                                   int K, int ldc) {
  GEMM_PROLOGUE_AND_LOOP
  const int r0 = kg * 4;
#pragma unroll
  for (int n = 0; n < 2; ++n) {
    int col = bn + w * 32 + n * 16 + fr;
    float bv = bias[col];
#pragma unroll
    for (int m = 0; m < 2; ++m) {
      int row = bm + m * 16 + r0;
#pragma unroll
      for (int r = 0; r < 4; ++r)
        C[(size_t)(row + r) * ldc + col] = acc[m][n][r] + bv;
    }
  }
}

// ---------------------------------------------------------------------------
// GEMM1 fused: qkv GEMM + bias + RoPE (table) + f16 hi/lo split + V transpose.
// Columns: [0,96)=k -> kh/kl; [96,192)=v -> vT (LDS transpose in As[0],
// coalesced stores); [192,960)=q -> qh/ql; >=960 pad (skipped).
// grid = (M/32, 8). RoPE pair (2f,2f+1): even lane computes BOTH outputs
// (bit-identical) -> paired f16x2 stores.
// ---------------------------------------------------------------------------
__global__ __launch_bounds__(256) void gemm_qkv_rope(const f16* __restrict__ A,
                                                     const f16* __restrict__ B,
                                                     const float* __restrict__ bias,
                                                     const float* __restrict__ ctab,
                                                     const float* __restrict__ stab,
                                                     f16* __restrict__ qh,
                                                     f16* __restrict__ ql,
                                                     f16* __restrict__ kh,
                                                     f16* __restrict__ kl,
                                                     f16* __restrict__ vT) {
  const int K = 768;
  GEMM_PROLOGUE_AND_LOOP
  const int r0 = kg * 4;
  // v-column transpose buffer overlaid on As (dead after the loop, which
  // ends with a barrier). stride 40 halves; 64 cols x 32 rows = 5 KB < 8 KB.
  f16* ls = &As[0][0];
  const int vlo = (bn < 96) ? 96 : bn;
  const int vhi = (bn + 128 < 192) ? (bn + 128) : 192;
  const bool has_v = vlo < vhi;                 // blocks y=0 (32 cols), y=1 (64)
  const bool even = !(fr & 1);
#pragma unroll
  for (int n = 0; n < 2; ++n) {
    int col = bn + w * 32 + n * 16 + fr;
    float bv = bias[col];
    int seg = (col * 683) >> 16;        // col / 96
    int f = (col - seg * 96) >> 1;
#pragma unroll
    for (int m = 0; m < 2; ++m) {
      int row = bm + m * 16 + r0;
      if (seg == 1) {                   // v column: pack 4 rows -> LDS
        f16x4 pk;
#pragma unroll
        for (int r = 0; r < 4; ++r) pk[r] = (f16)(acc[m][n][r] + bv);
        *(f16x4*)&ls[(col - vlo) * 40 + m * 16 + r0] = pk;
        continue;
      }
#pragma unroll
      for (int r = 0; r < 4; ++r) {
        float v = acc[m][n][r] + bv;
        float p = __shfl_xor(v, 1);     // partner column of the rope pair
        if (even && col < 960) {        // lane owns the (even,odd) pair
          float c = ctab[(row + r) * 48 + f];
          float s = stab[(row + r) * 48 + f];
          float re = v * c - p * s;
          float ro = v * s + p * c;
          f16 hie = (f16)re, hio = (f16)ro;
          f16x2 hv; hv[0] = hie; hv[1] = hio;
          f16x2 lv; lv[0] = (f16)(re - (float)hie); lv[1] = (f16)(ro - (float)hio);
          if (seg == 0) {
            *(f16x2*)(kh + (size_t)(row + r) * QD + col) = hv;
            *(f16x2*)(kl + (size_t)(row + r) * QD + col) = lv;
          } else {
            int qc = col - 192;
            *(f16x2*)(qh + (size_t)(row + r) * DM + qc) = hv;
            *(f16x2*)(ql + (size_t)(row + r) * DM + qc) = lv;
          }
        }
      }
    }
  }
  if (has_v) {                          // coalesced vT write-out
    __syncthreads();
    const int nv = vhi - vlo;           // 32 or 64
    for (int idx = t; idx < nv * 4; idx += 256) {
      int cl = idx >> 2, sg = idx & 3;
      *(half8*)(vT + (size_t)(vlo - 96 + cl) * 4096 + bm + sg * 8) =
          *(half8*)&ls[cl * 40 + sg * 8];
    }
  }
}

// ---------------------------------------------------------------------------
// MFMA windowed attention v3: block = 32-query tile x 2 heads, 4 waves
// (wave = 1 head x 16 queries x 160 keys, 9 live chunks). LDS 65.5 KB ->
// 2 blocks/CU = 8 waves/CU (the occupancy lever). k_lo read direct from
// global (L2-hot); P-scratch overlays kbuf after QK (1 barrier).
// grid = (L/32, 4).
// ---------------------------------------------------------------------------
__global__ __launch_bounds__(256) void attn3_kernel(const f16* __restrict__ qh,
                                                    const f16* __restrict__ ql,
                                                    const f16* __restrict__ kh,
                                                    const f16* __restrict__ kl,
                                                    const f16* __restrict__ vT,
                                                    f16* __restrict__ aout) {
  __shared__ f16 kbuf[160 * 104];      // K_hi tile; P-scratch after QK
  __shared__ f16 vbuf[96 * 168];       // vT tile [96][160+8]
  const int t  = threadIdx.x, w = t >> 6, l = t & 63;
  const int fr = l & 15, kg = l >> 4;
  const int i0 = blockIdx.x * 32;
  const int h  = blockIdx.y * 2 + (w >> 1);
  const int q0 = (w & 1) * 16;
  const int jbase = i0 - 128;
  const int nlo = w & 1;               // live key-chunks: [nlo, nlo+9)

  // stage K_hi tile (160 x 96 -> padded 104), coalesced
  for (int it = 0; it < 8; ++it) {
    int c = t + 256 * it;
    if (c < 1920) {
      int row = c / 12, seg = c - row * 12;
      int jabs = jbase + row; if (jabs < 0) jabs = 0;
      *(half8*)(kbuf + row * 104 + seg * 8) =
          *(const half8*)(kh + (size_t)jabs * QD + seg * 8);
    }
  }
  // stage vT tile (96 x 160 -> padded 168), coalesced
  for (int it = 0; it < 8; ++it) {
    int c = t + 256 * it;
    if (c < 1920) {
      int row = c / 20, seg = c - row * 20;
      int col0 = jbase + seg * 8; if (col0 < 0) col0 = 0;
      *(half8*)(vbuf + row * 168 + seg * 8) =
          *(const half8*)(vT + (size_t)row * 4096 + col0);
    }
  }

  // Q fragments (16 rows per wave)
  half8 a_h[3], a_l[3];
  {
    size_t qoff = (size_t)(i0 + q0 + fr) * DM + h * QD;
#pragma unroll
    for (int kc = 0; kc < 3; ++kc) {
      a_h[kc] = *(const half8*)(qh + qoff + kc * 32 + kg * 8);
      a_l[kc] = *(const half8*)(ql + qoff + kc * 32 + kg * 8);
    }
  }
  __syncthreads();

  // S = Q K^T  (hi*hi + lo*hi + hi*lo); k_lo gathered from global (L2-hot)
  f32x4 s[10];
#pragma unroll
  for (int n = 0; n < 10; ++n) s[n] = (f32x4){0.f, 0.f, 0.f, 0.f};

  __builtin_amdgcn_s_setprio(1);
#pragma unroll
  for (int n = 0; n < 10; ++n) {
    if (n < nlo || n >= nlo + 9) continue;
    int krow = n * 16 + fr;
    int jabs = jbase + krow; if (jabs < 0) jabs = 0;
#pragma unroll
    for (int kc = 0; kc < 3; ++kc) {
      half8 b_h = *(const half8*)(kbuf + krow * 104 + kc * 32 + kg * 8);
      half8 b_l = *(const half8*)(kl + (size_t)jabs * QD + kc * 32 + kg * 8);
      s[n] = MFMA16(a_h[kc], b_h, s[n]);
      s[n] = MFMA16(a_l[kc], b_h, s[n]);
      s[n] = MFMA16(a_h[kc], b_l, s[n]);
    }
  }
  __builtin_amdgcn_s_setprio(0);

  // mask + scale + softmax (rows in (kg, r); cols in (fr, n))
  const int jmin = (i0 < 128) ? (128 - i0) : 0;
  const float scale = 9.79795897113271f;
  float mx[4], sm[4], inv[4];
#pragma unroll
  for (int r = 0; r < 4; ++r) mx[r] = -1e30f;

#pragma unroll
  for (int n = 0; n < 10; ++n) {
    if (n < nlo || n >= nlo + 9) continue;
    int jloc = n * 16 + fr;
#pragma unroll
    for (int r = 0; r < 4; ++r) {
      int iloc = q0 + kg * 4 + r;
      bool valid = (jloc > iloc) && (jloc <= iloc + 128) && (jloc >= jmin);
      float v = valid ? s[n][r] * scale : -1e30f;
      s[n][r] = v;
      mx[r] = fmaxf(mx[r], v);
    }
  }
#pragma unroll
  for (int r = 0; r < 4; ++r) {
    float v = mx[r];
    v = fmaxf(v, __shfl_xor(v, 1));
    v = fmaxf(v, __shfl_xor(v, 2));
    v = fmaxf(v, __shfl_xor(v, 4));
    v = fmaxf(v, __shfl_xor(v, 8));
    mx[r] = v;
    sm[r] = 0.f;
  }
#pragma unroll
  for (int n = 0; n < 10; ++n) {
    if (n < nlo || n >= nlo + 9) { // dead chunks stay exactly 0
#pragma unroll
      for (int r = 0; r < 4; ++r) s[n][r] = 0.f;
      continue;
    }
#pragma unroll
    for (int r = 0; r < 4; ++r) {
      float p = __expf(s[n][r] - mx[r]);
      s[n][r] = p;
      sm[r] += p;
    }
  }
#pragma unroll
  for (int r = 0; r < 4; ++r) {
    float v = sm[r];
    v += __shfl_xor(v, 1);
    v += __shfl_xor(v, 2);
    v += __shfl_xor(v, 4);
    v += __shfl_xor(v, 8);
    inv[r] = 1.f / v;
  }

  // all waves done reading kbuf (QK) before reusing it as P-scratch
  __syncthreads();

  // PV over 5 key-chunks of 32 (c6*32 spans exactly the 160 keys); dead-n
  // P entries are exactly 0 and contribute nothing. P round-trips per-wave
  // scratch in kbuf (wave-private: same-wave DS ordering, no barriers).
  f16* pw = kbuf + w * 640;            // 16 rows x 40 halves per wave
  f32x4 o[6];
#pragma unroll
  for (int dn = 0; dn < 6; ++dn) o[dn] = (f32x4){0.f, 0.f, 0.f, 0.f};

#pragma unroll
  for (int c6 = 0; c6 < 5; ++c6) {
#pragma unroll
    for (int nn = 0; nn < 2; ++nn)
#pragma unroll
      for (int r = 0; r < 4; ++r)
        pw[(kg * 4 + r) * 40 + nn * 16 + fr] = (f16)s[2 * c6 + nn][r];
    half8 ap = *(half8*)(pw + fr * 40 + kg * 8);
    __builtin_amdgcn_s_setprio(1);
#pragma unroll
    for (int dn = 0; dn < 6; ++dn) {
      half8 bv = *(half8*)(vbuf + (dn * 16 + fr) * 168 + c6 * 32 + kg * 8);
      o[dn] = MFMA16(ap, bv, o[dn]);
    }
    __builtin_amdgcn_s_setprio(0);
  }

#pragma unroll
  for (int dn = 0; dn < 6; ++dn) {
    int col = h * QD + dn * 16 + fr;
#pragma unroll
    for (int r = 0; r < 4; ++r) {
      int row = i0 + q0 + kg * 4 + r;
      aout[(size_t)row * DM + col] = (f16)(o[dn][r] * inv[r]);
    }
  }
}

// ---------------------------------------------------------------------------
extern "C" void kernel_launch(void* const* d_in, const int* in_sizes, int n_in,
                              void* d_out, int out_size, void* d_ws, size_t ws_size,
                              hipStream_t stream) {
  const float* x    = (const float*)d_in[0];
  const float* Wqkv = (const float*)d_in[1];
  const float* bqkv = (const float*)d_in[2];
  const float* Wout = (const float*)d_in[3];
  const float* bout = (const float*)d_in[4];
  float* out = (float*)d_out;

  char* ws = (char*)d_ws;
  f16*   xh   = (f16*)(ws);                    // 6291456
  f16*   w1h  = (f16*)(ws + 6291456);          // 1572864
  f16*   w2h  = (f16*)(ws + 7864320);          // 1179648
  float* b1p  = (float*)(ws + 9043968);        // 4096
  float* ctab = (float*)(ws + 9048064);        // 786432
  float* stab = (float*)(ws + 9834496);        // 786432
  f16*   qh   = (f16*)(ws + 10620928);         // 6291456
  f16*   ql   = (f16*)(ws + 16912384);         // 6291456
  f16*   kh   = (f16*)(ws + 23203840);         // 786432
  f16*   kl   = (f16*)(ws + 23990272);         // 786432
  f16*   vT   = (f16*)(ws + 24776704);         // 786432
  f16*   aout = (f16*)(ws + 25563136);         // 6291456 -> total 31854592

  prep_kernel<<<dim3(5444), dim3(256), 0, stream>>>(x, Wqkv, bqkv, Wout,
                                                    xh, w1h, w2h, b1p, ctab, stab);
  gemm_qkv_rope<<<dim3(128, 8), dim3(256), 0, stream>>>(xh, w1h, b1p, ctab, stab,
                                                        qh, ql, kh, kl, vT);
  attn3_kernel<<<dim3(128, 4), dim3(256), 0, stream>>>(qh, ql, kh, kl, vT, aout);
  gemm_f16_tn<<<dim3(128, 6), dim3(256), 0, stream>>>(aout, w2h, bout, out, 768, 768);
}

// Round 14
// 55.581 us; speedup vs baseline: 1.5088x; 1.0306x over previous
//
#include <hip/hip_runtime.h>

typedef _Float16 f16;
typedef _Float16 half8 __attribute__((ext_vector_type(8)));
typedef _Float16 f16x2 __attribute__((ext_vector_type(2)));
typedef _Float16 f16x4 __attribute__((ext_vector_type(4)));
typedef float    f32x4 __attribute__((ext_vector_type(4)));

#define DM    768
#define QD    96
#define MFMA16(a,b,c) __builtin_amdgcn_mfma_f32_16x16x32_f16(a, b, c, 0, 0, 0)

// ---------------------------------------------------------------------------
__device__ __forceinline__ void async_copy16(const f16* g, f16* l) {
  __builtin_amdgcn_global_load_lds((const __attribute__((address_space(1))) void*)g,
                                   (__attribute__((address_space(3))) void*)l,
                                   16, 0, 0);
}

// ---------------------------------------------------------------------------
// prep: weight cast/pad (b<1348), sincos table (rest). x-cast is now fused
// into gemm1 (A staged from f32 x directly, cast in-register).
// ---------------------------------------------------------------------------
__global__ __launch_bounds__(256) void prep_kernel(const float* __restrict__ Wqkv,
                                                   const float* __restrict__ bqkv,
                                                   const float* __restrict__ Wout,
                                                   f16* __restrict__ w1h,
                                                   f16* __restrict__ w2h,
                                                   float* __restrict__ b1p,
                                                   float* __restrict__ ctab,
                                                   float* __restrict__ stab) {
  const int NW1 = 1024 * 768 / 4;
  const int NW2 = 768 * 768 / 4;
  int b = blockIdx.x;
  if (b < 1348) {                       // weights + bias
    int idx = b * 256 + threadIdx.x;
    if (idx < NW1) {
      int r = idx / 192;
      f16x4 o;
      if (r < 960) {
        f32x4 v = ((const f32x4*)Wqkv)[idx];
        o[0] = (f16)v[0]; o[1] = (f16)v[1]; o[2] = (f16)v[2]; o[3] = (f16)v[3];
      } else {
        o[0] = (f16)0.f; o[1] = (f16)0.f; o[2] = (f16)0.f; o[3] = (f16)0.f;
      }
      ((f16x4*)w1h)[idx] = o;
    } else if (idx < NW1 + NW2) {
      int j = idx - NW1;
      f32x4 v = ((const f32x4*)Wout)[j];
      f16x4 o;
      o[0] = (f16)v[0]; o[1] = (f16)v[1]; o[2] = (f16)v[2]; o[3] = (f16)v[3];
      ((f16x4*)w2h)[j] = o;
    } else {
      int j = idx - (NW1 + NW2);
      b1p[j] = (j < 960) ? bqkv[j] : 0.f;
    }
    return;
  }
  // sincos table: 4096 pos x 48 freqs (padded loop to 64, pow2 math)
  int idx = (b - 1348) * 256 + threadIdx.x;
  int pos = idx >> 6, f = idx & 63;
  if (f < 48) {
    float theta = exp2f((float)f * -0.27682734f);   // 10000^(-2f/96)
    float s, c;
    sincosf((float)pos * theta, &s, &c);
    ctab[pos * 48 + f] = c;
    stab[pos * 48 + f] = s;
  }
}

// ---------------------------------------------------------------------------
// shared GEMM macros (round-11 structure, the 54.9 best): 32x128 tile,
// 4 waves (each 32x32 out), BK=64, double-buffered LDS (40 KB -> 4 blocks/CU
// = 16 waves/CU), counted-vmcnt pipeline. LDS linear [row][64] halves;
// k-chunk XOR-swizzled (chunk ^ (row&7)) on BOTH staging source and ds_read
// address (rule #21).
// ---------------------------------------------------------------------------
#define GEMM_VM6  asm volatile("s_waitcnt vmcnt(6)" ::: "memory")
#define GEMM_VM5  asm volatile("s_waitcnt vmcnt(5)" ::: "memory")
#define GEMM_VM0  asm volatile("s_waitcnt vmcnt(0)" ::: "memory")
#define GEMM_LGK0 asm volatile("s_waitcnt lgkmcnt(0)" ::: "memory")
#define GEMM_SB   __builtin_amdgcn_s_barrier()
#define GEMM_SCB  __builtin_amdgcn_sched_barrier(0)

#define GEMM_COMPUTE(BUF)                                                      \
  do {                                                                         \
    half8 a[2][2], b[2][2];                                                    \
    _Pragma("unroll")                                                          \
    for (int m = 0; m < 2; ++m) {                                              \
      int row = m * 16 + fr;                                                   \
      _Pragma("unroll")                                                        \
      for (int kk = 0; kk < 2; ++kk) {                                         \
        int c = (kk << 2) | kg;                                                \
        a[m][kk] = *(const half8*)&As[BUF][row * 64 + ((c ^ (row & 7)) << 3)]; \
      }                                                                        \
    }                                                                          \
    _Pragma("unroll")                                                          \
    for (int n = 0; n < 2; ++n) {                                              \
      int row = w * 32 + n * 16 + fr;                                          \
      _Pragma("unroll")                                                        \
      for (int kk = 0; kk < 2; ++kk) {                                         \
        int c = (kk << 2) | kg;                                                \
        b[n][kk] = *(const half8*)&Bs[BUF][row * 64 + ((c ^ (row & 7)) << 3)]; \
      }                                                                        \
    }                                                                          \
    _Pragma("unroll")                                                          \
    for (int m = 0; m < 2; ++m)                                                \
      _Pragma("unroll")                                                        \
      for (int n = 0; n < 2; ++n) {                                            \
        acc[m][n] = MFMA16(a[m][0], b[n][0], acc[m][n]);                       \
        acc[m][n] = MFMA16(a[m][1], b[n][1], acc[m][n]);                       \
      }                                                                        \
  } while (0)

// ---------------------------------------------------------------------------
// GEMM2: C[M x ldc](f32) = A * B^T + bias; grid = (M/32, N/128).
// A and B both staged via global_load_lds (R11 verbatim).
// ---------------------------------------------------------------------------
#define GEMM2_STAGE(BUF, K0)                                        \
  do {                                                              \
    async_copy16(Ap + (K0),           lA0 + (BUF) * 2048);          \
    async_copy16(Bp + (K0),           lB0 + (BUF) * 8192);          \
    async_copy16(Bp + 32 * K + (K0),  lB0 + (BUF) * 8192 + 2048);   \
    async_copy16(Bp + 64 * K + (K0),  lB0 + (BUF) * 8192 + 4096);   \
    async_copy16(Bp + 96 * K + (K0),  lB0 + (BUF) * 8192 + 6144);   \
  } while (0)

__global__ __launch_bounds__(256) void gemm_f16_tn(const f16* __restrict__ A,
                                                   const f16* __restrict__ B,
                                                   const float* __restrict__ bias,
                                                   float* __restrict__ C,
                                                   int K, int ldc) {
  __shared__ f16 As[2][32 * 64];
  __shared__ f16 Bs[2][128 * 64];
  const int t  = threadIdx.x;
  const int bm = blockIdx.x * 32;
  const int bn = blockIdx.y * 128;
  const int w  = t >> 6, l = t & 63;
  const int fr = l & 15, kg = l >> 4;
  f32x4 acc[2][2] = {};
  const int srow = t >> 3;
  const int skc  = ((t & 7) ^ (srow & 7)) << 3;
  const f16* Ap = A + (size_t)(bm + srow) * K + skc;
  const f16* Bp = B + (size_t)(bn + srow) * K + skc;
  f16* lA0 = &As[0][t * 8];
  f16* lB0 = &Bs[0][t * 8];
  const int nt = K >> 6;
  GEMM2_STAGE(0, 0);
  GEMM2_STAGE(1, 64);
  for (int tk = 0; tk < nt; ++tk) {
    if (tk + 1 < nt) { GEMM_VM5; } else { GEMM_VM0; }
    GEMM_SB; GEMM_SCB;
    GEMM_COMPUTE(tk & 1);
    GEMM_SCB; GEMM_SB;
    if (tk + 2 < nt) GEMM2_STAGE(tk & 1, (tk + 2) << 6);
  }
  const int r0 = kg * 4;
#pragma unroll
  for (int n = 0; n < 2; ++n) {
    int col = bn + w * 32 + n * 16 + fr;
    float bv = bias[col];
#pragma unroll
    for (int m = 0; m < 2; ++m) {
      int row = bm + m * 16 + r0;
#pragma unroll
      for (int r = 0; r < 4; ++r)
        C[(size_t)(row + r) * ldc + col] = acc[m][n][r] + bv;
    }
  }
}

// ---------------------------------------------------------------------------
// GEMM1 fused: qkv GEMM (A = x in f32, cast fused into staging) + bias +
// RoPE (table) + f16 hi/lo split + V transpose. A-tile reg-staged:
// 2x f32x4 global loads (issued BEFORE the B gl_lds so the A ds_write's
// auto-wait leaves B(t+1) in flight) -> cvt f16 (bit-identical to the old
// separate cast) -> ds_write_b128 into the same swizzled layout.
// Columns: [0,96)=k -> kh/kl; [96,192)=v -> vT; [192,960)=q -> qh/ql.
// grid = (M/32, 8).
// ---------------------------------------------------------------------------
#define G1_LOAD_A(SB, K0)                                           \
  do {                                                              \
    sa[SB][0] = *(const f32x4*)(Xp + (K0));                         \
    sa[SB][1] = *(const f32x4*)(Xp + (K0) + 4);                     \
  } while (0)

#define G1_STAGE_B(BUF, K0)                                         \
  do {                                                              \
    async_copy16(Bp + (K0),           lB0 + (BUF) * 8192);          \
    async_copy16(Bp + 32 * K + (K0),  lB0 + (BUF) * 8192 + 2048);   \
    async_copy16(Bp + 64 * K + (K0),  lB0 + (BUF) * 8192 + 4096);   \
    async_copy16(Bp + 96 * K + (K0),  lB0 + (BUF) * 8192 + 6144);   \
  } while (0)

#define G1_WRITE_A(BUF, SB)                                         \
  do {                                                              \
    half8 pk;                                                       \
    _Pragma("unroll")                                               \
    for (int j = 0; j < 4; ++j) {                                   \
      pk[j]     = (f16)sa[SB][0][j];                                \
      pk[4 + j] = (f16)sa[SB][1][j];                                \
    }                                                               \
    *(half8*)&As[BUF][t * 8] = pk;                                  \
  } while (0)

__global__ __launch_bounds__(256) void gemm_qkv_rope(const float* __restrict__ X,
                                                     const f16* __restrict__ B,
                                                     const float* __restrict__ bias,
                                                     const float* __restrict__ ctab,
                                                     const float* __restrict__ stab,
                                                     f16* __restrict__ qh,
                                                     f16* __restrict__ ql,
                                                     f16* __restrict__ kh,
                                                     f16* __restrict__ kl,
                                                     f16* __restrict__ vT) {
  const int K = 768;
  __shared__ f16 As[2][32 * 64];
  __shared__ f16 Bs[2][128 * 64];
  const int t  = threadIdx.x;
  const int bm = blockIdx.x * 32;
  const int bn = blockIdx.y * 128;
  const int w  = t >> 6, l = t & 63;
  const int fr = l & 15, kg = l >> 4;
  f32x4 acc[2][2] = {};
  const int srow = t >> 3;
  const int skc  = ((t & 7) ^ (srow & 7)) << 3;
  const float* Xp = X + (size_t)(bm + srow) * 768 + skc;
  const f16* Bp = B + (size_t)(bn + srow) * K + skc;
  f16* lB0 = &Bs[0][t * 8];
  const int nt = 12;                   // 768/64
  f32x4 sa[2][2];
  // prologue: A loads BEFORE B stages (keeps B prefetch deep under auto-waits)
  G1_LOAD_A(0, 0);   G1_STAGE_B(0, 0);
  G1_LOAD_A(1, 64);  G1_STAGE_B(1, 64);
  G1_WRITE_A(0, 0);                    // compiler auto-waits A(0) loads only
  for (int tk = 0; tk < nt; ++tk) {
    if (tk + 1 < nt) { GEMM_VM6; } else { GEMM_VM0; }
    GEMM_LGK0;                         // publish A ds_write before barrier
    GEMM_SB; GEMM_SCB;
    GEMM_COMPUTE(tk & 1);
    GEMM_SCB; GEMM_SB;
    if (tk + 2 < nt) { G1_LOAD_A(tk & 1, (tk + 2) << 6); G1_STAGE_B(tk & 1, (tk + 2) << 6); }
    if (tk + 1 < nt) { G1_WRITE_A(1 - (tk & 1), 1 - (tk & 1)); }
  }
  const int r0 = kg * 4;
  // v-column transpose buffer overlaid on As (dead after the loop, which
  // ends with a barrier). stride 40 halves; 64 cols x 32 rows = 5 KB.
  f16* ls = &As[0][0];
  const int vlo = (bn < 96) ? 96 : bn;
  const int vhi = (bn + 128 < 192) ? (bn + 128) : 192;
  const bool has_v = vlo < vhi;                 // blocks y=0 (32 cols), y=1 (64)
  const bool even = !(fr & 1);
#pragma unroll
  for (int n = 0; n < 2; ++n) {
    int col = bn + w * 32 + n * 16 + fr;
    float bv = bias[col];
    int seg = (col * 683) >> 16;        // col / 96
    int f = (col - seg * 96) >> 1;
#pragma unroll
    for (int m = 0; m < 2; ++m) {
      int row = bm + m * 16 + r0;
      if (seg == 1) {                   // v column: pack 4 rows -> LDS
        f16x4 pk;
#pragma unroll
        for (int r = 0; r < 4; ++r) pk[r] = (f16)(acc[m][n][r] + bv);
        *(f16x4*)&ls[(col - vlo) * 40 + m * 16 + r0] = pk;
        continue;
      }
#pragma unroll
      for (int r = 0; r < 4; ++r) {
        float v = acc[m][n][r] + bv;
        float p = __shfl_xor(v, 1);     // partner column of the rope pair
        if (even && col < 960) {        // lane owns the (even,odd) pair
          float c = ctab[(row + r) * 48 + f];
          float s = stab[(row + r) * 48 + f];
          float re = v * c - p * s;
          float ro = v * s + p * c;
          f16 hie = (f16)re, hio = (f16)ro;
          f16x2 hv; hv[0] = hie; hv[1] = hio;
          f16x2 lv; lv[0] = (f16)(re - (float)hie); lv[1] = (f16)(ro - (float)hio);
          if (seg == 0) {
            *(f16x2*)(kh + (size_t)(row + r) * QD + col) = hv;
            *(f16x2*)(kl + (size_t)(row + r) * QD + col) = lv;
          } else {
            int qc = col - 192;
            *(f16x2*)(qh + (size_t)(row + r) * DM + qc) = hv;
            *(f16x2*)(ql + (size_t)(row + r) * DM + qc) = lv;
          }
        }
      }
    }
  }
  if (has_v) {                          // coalesced vT write-out
    __syncthreads();
    const int nv = vhi - vlo;           // 32 or 64
    for (int idx = t; idx < nv * 4; idx += 256) {
      int cl = idx >> 2, sg = idx & 3;
      *(half8*)(vT + (size_t)(vlo - 96 + cl) * 4096 + bm + sg * 8) =
          *(half8*)&ls[cl * 40 + sg * 8];
    }
  }
}

// ---------------------------------------------------------------------------
// MFMA windowed attention (round-9 attn2, the proven best).
// ---------------------------------------------------------------------------
__global__ __launch_bounds__(256) void attn2_kernel(const f16* __restrict__ qh,
                                                    const f16* __restrict__ ql,
                                                    const f16* __restrict__ kh,
                                                    const f16* __restrict__ kl,
                                                    const f16* __restrict__ vT,
                                                    f16* __restrict__ aout) {
  __shared__ f16 kbuf[192 * 104];      // K_hi tile
  __shared__ f16 klbuf[192 * 104];     // K_lo tile
  __shared__ f16 vbuf[96 * 200];       // vT tile [96][200]
  __shared__ f16 pbuf[4][32 * 40];     // per-wave P chunk (wave-private)
  const int t  = threadIdx.x, w = t >> 6, l = t & 63;
  const int fr = l & 15, kg = l >> 4;
  const int i0 = blockIdx.x * 64;
  const int h  = blockIdx.y * 2 + (w >> 1);
  const int q0 = (w & 1) * 32;
  const int jbase = i0 - 128;
  const int nlo = (w & 1) ? 2 : 0;     // live key-chunks: [nlo, nlo+10)

  // stage K_hi + K_lo tiles (192 x 96 -> padded 104), coalesced
  for (int it = 0; it < 9; ++it) {
    int c = t + 256 * it;
    int row = c / 12, seg = c - row * 12;
    int jabs = jbase + row; if (jabs < 0) jabs = 0;
    *(half8*)(kbuf + row * 104 + seg * 8) =
        *(const half8*)(kh + (size_t)jabs * QD + seg * 8);
    *(half8*)(klbuf + row * 104 + seg * 8) =
        *(const half8*)(kl + (size_t)jabs * QD + seg * 8);
  }
  // stage vT tile (96 x 192 -> padded 200), coalesced
  for (int it = 0; it < 9; ++it) {
    int c = t + 256 * it;
    int row = c / 24, seg = c - row * 24;
    int col0 = jbase + seg * 8; if (col0 < 0) col0 = 0;
    *(half8*)(vbuf + row * 200 + seg * 8) =
        *(const half8*)(vT + (size_t)row * 4096 + col0);
  }

  half8 a_h[2][3], a_l[2][3];
#pragma unroll
  for (int m = 0; m < 2; ++m) {
    size_t qoff = (size_t)(i0 + q0 + m * 16 + fr) * DM + h * QD;
#pragma unroll
    for (int kc = 0; kc < 3; ++kc) {
      a_h[m][kc] = *(const half8*)(qh + qoff + kc * 32 + kg * 8);
      a_l[m][kc] = *(const half8*)(ql + qoff + kc * 32 + kg * 8);
    }
  }
  __syncthreads();

  // S = Q K^T  (hi*hi + lo*hi + hi*lo)
  f32x4 s[2][12];
#pragma unroll
  for (int m = 0; m < 2; ++m)
#pragma unroll
    for (int n = 0; n < 12; ++n)
      s[m][n] = (f32x4){0.f, 0.f, 0.f, 0.f};

  __builtin_amdgcn_s_setprio(1);
#pragma unroll
  for (int n = 0; n < 12; ++n) {
    if (n < nlo || n >= nlo + 10) continue;
    int krow = n * 16 + fr;
#pragma unroll
    for (int kc = 0; kc < 3; ++kc) {
      half8 b_h = *(const half8*)(kbuf + krow * 104 + kc * 32 + kg * 8);
      half8 b_l = *(const half8*)(klbuf + krow * 104 + kc * 32 + kg * 8);
      s[0][n] = MFMA16(a_h[0][kc], b_h, s[0][n]);
      s[1][n] = MFMA16(a_h[1][kc], b_h, s[1][n]);
      s[0][n] = MFMA16(a_l[0][kc], b_h, s[0][n]);
      s[1][n] = MFMA16(a_l[1][kc], b_h, s[1][n]);
      s[0][n] = MFMA16(a_h[0][kc], b_l, s[0][n]);
      s[1][n] = MFMA16(a_h[1][kc], b_l, s[1][n]);
    }
  }
  __builtin_amdgcn_s_setprio(0);

  // mask + scale + softmax
  const int jmin = (i0 < 128) ? (128 - i0) : 0;
  const float scale = 9.79795897113271f;
  float mx[2][4], sm[2][4], inv[2][4];
#pragma unroll
  for (int m = 0; m < 2; ++m)
#pragma unroll
    for (int r = 0; r < 4; ++r) mx[m][r] = -1e30f;

#pragma unroll
  for (int m = 0; m < 2; ++m)
#pragma unroll
    for (int n = 0; n < 12; ++n) {
      if (n < nlo || n >= nlo + 10) continue;
      int jloc = n * 16 + fr;
#pragma unroll
      for (int r = 0; r < 4; ++r) {
        int iloc = q0 + m * 16 + kg * 4 + r;
        bool valid = (jloc > iloc) && (jloc <= iloc + 128) && (jloc >= jmin);
        float v = valid ? s[m][n][r] * scale : -1e30f;
        s[m][n][r] = v;
        mx[m][r] = fmaxf(mx[m][r], v);
      }
    }
#pragma unroll
  for (int m = 0; m < 2; ++m)
#pragma unroll
    for (int r = 0; r < 4; ++r) {
      float v = mx[m][r];
      v = fmaxf(v, __shfl_xor(v, 1));
      v = fmaxf(v, __shfl_xor(v, 2));
      v = fmaxf(v, __shfl_xor(v, 4));
      v = fmaxf(v, __shfl_xor(v, 8));
      mx[m][r] = v;
      sm[m][r] = 0.f;
    }
#pragma unroll
  for (int m = 0; m < 2; ++m)
#pragma unroll
    for (int n = 0; n < 12; ++n) {
      if (n < nlo || n >= nlo + 10) continue;
#pragma unroll
      for (int r = 0; r < 4; ++r) {
        float p = __expf(s[m][n][r] - mx[m][r]);
        s[m][n][r] = p;
        sm[m][r] += p;
      }
    }
#pragma unroll
  for (int m = 0; m < 2; ++m)
#pragma unroll
    for (int r = 0; r < 4; ++r) {
      float v = sm[m][r];
      v += __shfl_xor(v, 1);
      v += __shfl_xor(v, 2);
      v += __shfl_xor(v, 4);
      v += __shfl_xor(v, 8);
      inv[m][r] = 1.f / v;
    }

  // PV over live key-chunks (pbuf wave-private: same-wave DS ordering, no barriers)
  f16* pw = pbuf[w];
  const int c6lo = nlo >> 1;           // 5 of 6 chunks live
  f32x4 o[2][6];
#pragma unroll
  for (int m = 0; m < 2; ++m)
#pragma unroll
    for (int dn = 0; dn < 6; ++dn)
      o[m][dn] = (f32x4){0.f, 0.f, 0.f, 0.f};

#pragma unroll
  for (int c6 = 0; c6 < 6; ++c6) {
    if (c6 < c6lo || c6 >= c6lo + 5) continue;
#pragma unroll
    for (int m = 0; m < 2; ++m)
#pragma unroll
      for (int nn = 0; nn < 2; ++nn)
#pragma unroll
        for (int r = 0; r < 4; ++r)
          pw[(m * 16 + kg * 4 + r) * 40 + nn * 16 + fr] = (f16)s[m][2 * c6 + nn][r];
    half8 ap0 = *(half8*)(pw + fr * 40 + kg * 8);
    half8 ap1 = *(half8*)(pw + (16 + fr) * 40 + kg * 8);
    __builtin_amdgcn_s_setprio(1);
#pragma unroll
    for (int dn = 0; dn < 6; ++dn) {
      half8 bv = *(half8*)(vbuf + (dn * 16 + fr) * 200 + c6 * 32 + kg * 8);
      o[0][dn] = MFMA16(ap0, bv, o[0][dn]);
      o[1][dn] = MFMA16(ap1, bv, o[1][dn]);
    }
    __builtin_amdgcn_s_setprio(0);
  }

#pragma unroll
  for (int m = 0; m < 2; ++m)
#pragma unroll
    for (int dn = 0; dn < 6; ++dn) {
      int col = h * QD + dn * 16 + fr;
#pragma unroll
      for (int r = 0; r < 4; ++r) {
        int row = i0 + q0 + m * 16 + kg * 4 + r;
        aout[(size_t)row * DM + col] = (f16)(o[m][dn][r] * inv[m][r]);
      }
    }
}

// ---------------------------------------------------------------------------
extern "C" void kernel_launch(void* const* d_in, const int* in_sizes, int n_in,
                              void* d_out, int out_size, void* d_ws, size_t ws_size,
                              hipStream_t stream) {
  const float* x    = (const float*)d_in[0];
  const float* Wqkv = (const float*)d_in[1];
  const float* bqkv = (const float*)d_in[2];
  const float* Wout = (const float*)d_in[3];
  const float* bout = (const float*)d_in[4];
  float* out = (float*)d_out;

  char* ws = (char*)d_ws;
  f16*   w1h  = (f16*)(ws + 6291456);          // 1572864
  f16*   w2h  = (f16*)(ws + 7864320);          // 1179648
  float* b1p  = (float*)(ws + 9043968);        // 4096
  float* ctab = (float*)(ws + 9048064);        // 786432
  float* stab = (float*)(ws + 9834496);        // 786432
  f16*   qh   = (f16*)(ws + 10620928);         // 6291456
  f16*   ql   = (f16*)(ws + 16912384);         // 6291456
  f16*   kh   = (f16*)(ws + 23203840);         // 786432
  f16*   kl   = (f16*)(ws + 23990272);         // 786432
  f16*   vT   = (f16*)(ws + 24776704);         // 786432
  f16*   aout = (f16*)(ws + 25563136);         // 6291456 -> total 31854592

  prep_kernel<<<dim3(2372), dim3(256), 0, stream>>>(Wqkv, bqkv, Wout,
                                                    w1h, w2h, b1p, ctab, stab);
  gemm_qkv_rope<<<dim3(128, 8), dim3(256), 0, stream>>>(x, w1h, b1p, ctab, stab,
                                                        qh, ql, kh, kl, vT);
  attn2_kernel<<<dim3(64, 4), dim3(256), 0, stream>>>(qh, ql, kh, kl, vT, aout);
  gemm_f16_tn<<<dim3(128, 6), dim3(256), 0, stream>>>(aout, w2h, bout, out, 768, 768);
}

// Round 15
// 55.214 us; speedup vs baseline: 1.5188x; 1.0067x over previous
//
#include <hip/hip_runtime.h>

typedef _Float16 f16;
typedef _Float16 half8 __attribute__((ext_vector_type(8)));
typedef _Float16 f16x2 __attribute__((ext_vector_type(2)));
typedef _Float16 f16x4 __attribute__((ext_vector_type(4)));
typedef float    f32x4 __attribute__((ext_vector_type(4)));

#define DM    768
#define QD    96
#define MFMA16(a,b,c) __builtin_amdgcn_mfma_f32_16x16x32_f16(a, b, c, 0, 0, 0)

// ---------------------------------------------------------------------------
__device__ __forceinline__ void async_copy16(const f16* g, f16* l) {
  __builtin_amdgcn_global_load_lds((const __attribute__((address_space(1))) void*)g,
                                   (__attribute__((address_space(3))) void*)l,
                                   16, 0, 0);
}

// ---------------------------------------------------------------------------
// merged prep: x cast (b<3072), weight cast/pad (b<4420), sincos table (rest)
// ---------------------------------------------------------------------------
__global__ __launch_bounds__(256) void prep_kernel(const float* __restrict__ x,
                                                   const float* __restrict__ Wqkv,
                                                   const float* __restrict__ bqkv,
                                                   const float* __restrict__ Wout,
                                                   f16* __restrict__ xh,
                                                   f16* __restrict__ w1h,
                                                   f16* __restrict__ w2h,
                                                   float* __restrict__ b1p,
                                                   float* __restrict__ ctab,
                                                   float* __restrict__ stab) {
  const int NW1 = 1024 * 768 / 4;
  const int NW2 = 768 * 768 / 4;
  int b = blockIdx.x;
  if (b < 3072) {                       // x cast: 4096*768/4 items
    int idx = b * 256 + threadIdx.x;
    f32x4 v = ((const f32x4*)x)[idx];
    f16x4 o;
    o[0] = (f16)v[0]; o[1] = (f16)v[1]; o[2] = (f16)v[2]; o[3] = (f16)v[3];
    ((f16x4*)xh)[idx] = o;
    return;
  }
  if (b < 4420) {                       // weights + bias
    int idx = (b - 3072) * 256 + threadIdx.x;
    if (idx < NW1) {
      int r = idx / 192;
      f16x4 o;
      if (r < 960) {
        f32x4 v = ((const f32x4*)Wqkv)[idx];
        o[0] = (f16)v[0]; o[1] = (f16)v[1]; o[2] = (f16)v[2]; o[3] = (f16)v[3];
      } else {
        o[0] = (f16)0.f; o[1] = (f16)0.f; o[2] = (f16)0.f; o[3] = (f16)0.f;
      }
      ((f16x4*)w1h)[idx] = o;
    } else if (idx < NW1 + NW2) {
      int j = idx - NW1;
      f32x4 v = ((const f32x4*)Wout)[j];
      f16x4 o;
      o[0] = (f16)v[0]; o[1] = (f16)v[1]; o[2] = (f16)v[2]; o[3] = (f16)v[3];
      ((f16x4*)w2h)[j] = o;
    } else {
      int j = idx - (NW1 + NW2);
      b1p[j] = (j < 960) ? bqkv[j] : 0.f;
    }
    return;
  }
  // sincos table: 4096 pos x 48 freqs (padded loop to 64, pow2 math)
  int idx = (b - 4420) * 256 + threadIdx.x;
  int pos = idx >> 6, f = idx & 63;
  if (f < 48) {
    float theta = exp2f((float)f * -0.27682734f);   // 10000^(-2f/96)
    float s, c;
    sincosf((float)pos * theta, &s, &c);
    ctab[pos * 48 + f] = c;
    stab[pos * 48 + f] = s;
  }
}

// ---------------------------------------------------------------------------
// shared GEMM macros (round-11 structure, the proven best): 32x128 tile,
// 4 waves (each 32x32 out), BK=64, double-buffered LDS (40 KB -> 4 blocks/CU
// = 16 waves/CU), counted-vmcnt pipeline. LDS linear [row][64] halves;
// k-chunk XOR-swizzled (chunk ^ (row&7)) on BOTH staging source and ds_read
// address (rule #21).
// ---------------------------------------------------------------------------
#define GEMM_VM5  asm volatile("s_waitcnt vmcnt(5)" ::: "memory")
#define GEMM_VM0  asm volatile("s_waitcnt vmcnt(0)" ::: "memory")
#define GEMM_SB   __builtin_amdgcn_s_barrier()
#define GEMM_SCB  __builtin_amdgcn_sched_barrier(0)

#define GEMM_STAGE(BUF, K0)                                         \
  do {                                                              \
    async_copy16(Ap + (K0),           lA0 + (BUF) * 2048);          \
    async_copy16(Bp + (K0),           lB0 + (BUF) * 8192);          \
    async_copy16(Bp + 32 * K + (K0),  lB0 + (BUF) * 8192 + 2048);   \
    async_copy16(Bp + 64 * K + (K0),  lB0 + (BUF) * 8192 + 4096);   \
    async_copy16(Bp + 96 * K + (K0),  lB0 + (BUF) * 8192 + 6144);   \
  } while (0)

#define GEMM_COMPUTE(BUF)                                                      \
  do {                                                                         \
    half8 a[2][2], b[2][2];                                                    \
    _Pragma("unroll")                                                          \
    for (int m = 0; m < 2; ++m) {                                              \
      int row = m * 16 + fr;                                                   \
      _Pragma("unroll")                                                        \
      for (int kk = 0; kk < 2; ++kk) {                                         \
        int c = (kk << 2) | kg;                                                \
        a[m][kk] = *(const half8*)&As[BUF][row * 64 + ((c ^ (row & 7)) << 3)]; \
      }                                                                        \
    }                                                                          \
    _Pragma("unroll")                                                          \
    for (int n = 0; n < 2; ++n) {                                              \
      int row = w * 32 + n * 16 + fr;                                          \
      _Pragma("unroll")                                                        \
      for (int kk = 0; kk < 2; ++kk) {                                         \
        int c = (kk << 2) | kg;                                                \
        b[n][kk] = *(const half8*)&Bs[BUF][row * 64 + ((c ^ (row & 7)) << 3)]; \
      }                                                                        \
    }                                                                          \
    _Pragma("unroll")                                                          \
    for (int m = 0; m < 2; ++m)                                                \
      _Pragma("unroll")                                                        \
      for (int n = 0; n < 2; ++n) {                                            \
        acc[m][n] = MFMA16(a[m][0], b[n][0], acc[m][n]);                       \
        acc[m][n] = MFMA16(a[m][1], b[n][1], acc[m][n]);                       \
      }                                                                        \
  } while (0)

#define GEMM_PROLOGUE_AND_LOOP                                      \
  __shared__ f16 As[2][32 * 64];                                    \
  __shared__ f16 Bs[2][128 * 64];                                   \
  const int t  = threadIdx.x;                                       \
  const int bm = blockIdx.x * 32;                                   \
  const int bn = blockIdx.y * 128;                                  \
  const int w  = t >> 6, l = t & 63;                                \
  const int fr = l & 15, kg = l >> 4;                               \
  f32x4 acc[2][2] = {};                                             \
  const int srow = t >> 3;                                          \
  const int skc  = ((t & 7) ^ (srow & 7)) << 3;  /* swizzled src k */ \
  const f16* Ap = A + (size_t)(bm + srow) * K + skc;                \
  const f16* Bp = B + (size_t)(bn + srow) * K + skc;                \
  f16* lA0 = &As[0][t * 8];                                         \
  f16* lB0 = &Bs[0][t * 8];                                         \
  const int nt = K >> 6; /* >= 3 */                                 \
  GEMM_STAGE(0, 0);                                                 \
  GEMM_STAGE(1, 64);                                                \
  for (int tk = 0; tk < nt; ++tk) {                                 \
    if (tk + 1 < nt) { GEMM_VM5; } else { GEMM_VM0; }               \
    GEMM_SB; GEMM_SCB;                                              \
    GEMM_COMPUTE(tk & 1);                                           \
    GEMM_SCB; GEMM_SB;                                              \
    if (tk + 2 < nt) GEMM_STAGE(tk & 1, (tk + 2) << 6);             \
  }

// ---------------------------------------------------------------------------
// GEMM2: C[M x ldc](f32) = A * B^T + bias; grid = (M/32, N/128)
// ---------------------------------------------------------------------------
__global__ __launch_bounds__(256) void gemm_f16_tn(const f16* __restrict__ A,
                                                   const f16* __restrict__ B,
                                                   const float* __restrict__ bias,
                                                   float* __restrict__ C,
                                                   int K, int ldc) {
  GEMM_PROLOGUE_AND_LOOP
  const int r0 = kg * 4;
#pragma unroll
  for (int n = 0; n < 2; ++n) {
    int col = bn + w * 32 + n * 16 + fr;
    float bv = bias[col];
#pragma unroll
    for (int m = 0; m < 2; ++m) {
      int row = bm + m * 16 + r0;
#pragma unroll
      for (int r = 0; r < 4; ++r)
        C[(size_t)(row + r) * ldc + col] = acc[m][n][r] + bv;
    }
  }
}

// ---------------------------------------------------------------------------
// GEMM1 fused: qkv GEMM + bias + RoPE (table) + f16 hi/lo split + V transpose.
// Columns: [0,96)=k -> kh/kl; [96,192)=v -> vT (LDS transpose in As[0],
// coalesced stores); [192,960)=q -> qh/ql; >=960 pad (skipped).
// grid = (M/32, 8). RoPE pair (2f,2f+1): even lane computes BOTH outputs
// (bit-identical) -> paired f16x2 stores.
// ---------------------------------------------------------------------------
__global__ __launch_bounds__(256) void gemm_qkv_rope(const f16* __restrict__ A,
                                                     const f16* __restrict__ B,
                                                     const float* __restrict__ bias,
                                                     const float* __restrict__ ctab,
                                                     const float* __restrict__ stab,
                                                     f16* __restrict__ qh,
                                                     f16* __restrict__ ql,
                                                     f16* __restrict__ kh,
                                                     f16* __restrict__ kl,
                                                     f16* __restrict__ vT) {
  const int K = 768;
  GEMM_PROLOGUE_AND_LOOP
  const int r0 = kg * 4;
  // v-column transpose buffer overlaid on As (dead after the loop, which
  // ends with a barrier). stride 40 halves; 64 cols x 32 rows = 5 KB < 8 KB.
  f16* ls = &As[0][0];
  const int vlo = (bn < 96) ? 96 : bn;
  const int vhi = (bn + 128 < 192) ? (bn + 128) : 192;
  const bool has_v = vlo < vhi;                 // blocks y=0 (32 cols), y=1 (64)
  const bool even = !(fr & 1);
#pragma unroll
  for (int n = 0; n < 2; ++n) {
    int col = bn + w * 32 + n * 16 + fr;
    float bv = bias[col];
    int seg = (col * 683) >> 16;        // col / 96
    int f = (col - seg * 96) >> 1;
#pragma unroll
    for (int m = 0; m < 2; ++m) {
      int row = bm + m * 16 + r0;
      if (seg == 1) {                   // v column: pack 4 rows -> LDS
        f16x4 pk;
#pragma unroll
        for (int r = 0; r < 4; ++r) pk[r] = (f16)(acc[m][n][r] + bv);
        *(f16x4*)&ls[(col - vlo) * 40 + m * 16 + r0] = pk;
        continue;
      }
#pragma unroll
      for (int r = 0; r < 4; ++r) {
        float v = acc[m][n][r] + bv;
        float p = __shfl_xor(v, 1);     // partner column of the rope pair
        if (even && col < 960) {        // lane owns the (even,odd) pair
          float c = ctab[(row + r) * 48 + f];
          float s = stab[(row + r) * 48 + f];
          float re = v * c - p * s;
          float ro = v * s + p * c;
          f16 hie = (f16)re, hio = (f16)ro;
          f16x2 hv; hv[0] = hie; hv[1] = hio;
          f16x2 lv; lv[0] = (f16)(re - (float)hie); lv[1] = (f16)(ro - (float)hio);
          if (seg == 0) {
            *(f16x2*)(kh + (size_t)(row + r) * QD + col) = hv;
            *(f16x2*)(kl + (size_t)(row + r) * QD + col) = lv;
          } else {
            int qc = col - 192;
            *(f16x2*)(qh + (size_t)(row + r) * DM + qc) = hv;
            *(f16x2*)(ql + (size_t)(row + r) * DM + qc) = lv;
          }
        }
      }
    }
  }
  if (has_v) {                          // coalesced vT write-out
    __syncthreads();
    const int nv = vhi - vlo;           // 32 or 64
    for (int idx = t; idx < nv * 4; idx += 256) {
      int cl = idx >> 2, sg = idx & 3;
      *(half8*)(vT + (size_t)(vlo - 96 + cl) * 4096 + bm + sg * 8) =
          *(half8*)&ls[cl * 40 + sg * 8];
    }
  }
}

// ---------------------------------------------------------------------------
// MFMA windowed attention (round-9 attn2, proven best) with Q-fragment
// loads hoisted ABOVE the K/V staging loop (T14 issue-early: the Q loads
// are independent of the staging stores and consumed only after the
// barrier, so issuing them first hides their latency under staging).
// ---------------------------------------------------------------------------
__global__ __launch_bounds__(256) void attn2_kernel(const f16* __restrict__ qh,
                                                    const f16* __restrict__ ql,
                                                    const f16* __restrict__ kh,
                                                    const f16* __restrict__ kl,
                                                    const f16* __restrict__ vT,
                                                    f16* __restrict__ aout) {
  __shared__ f16 kbuf[192 * 104];      // K_hi tile
  __shared__ f16 klbuf[192 * 104];     // K_lo tile
  __shared__ f16 vbuf[96 * 200];       // vT tile [96][200]
  __shared__ f16 pbuf[4][32 * 40];     // per-wave P chunk (wave-private)
  const int t  = threadIdx.x, w = t >> 6, l = t & 63;
  const int fr = l & 15, kg = l >> 4;
  const int i0 = blockIdx.x * 64;
  const int h  = blockIdx.y * 2 + (w >> 1);
  const int q0 = (w & 1) * 32;
  const int jbase = i0 - 128;
  const int nlo = (w & 1) ? 2 : 0;     // live key-chunks: [nlo, nlo+10)

  // Q fragments first (consumed after the barrier; latency hides under staging)
  half8 a_h[2][3], a_l[2][3];
#pragma unroll
  for (int m = 0; m < 2; ++m) {
    size_t qoff = (size_t)(i0 + q0 + m * 16 + fr) * DM + h * QD;
#pragma unroll
    for (int kc = 0; kc < 3; ++kc) {
      a_h[m][kc] = *(const half8*)(qh + qoff + kc * 32 + kg * 8);
      a_l[m][kc] = *(const half8*)(ql + qoff + kc * 32 + kg * 8);
    }
  }

  // stage K_hi + K_lo tiles (192 x 96 -> padded 104), coalesced
  for (int it = 0; it < 9; ++it) {
    int c = t + 256 * it;
    int row = c / 12, seg = c - row * 12;
    int jabs = jbase + row; if (jabs < 0) jabs = 0;
    *(half8*)(kbuf + row * 104 + seg * 8) =
        *(const half8*)(kh + (size_t)jabs * QD + seg * 8);
    *(half8*)(klbuf + row * 104 + seg * 8) =
        *(const half8*)(kl + (size_t)jabs * QD + seg * 8);
  }
  // stage vT tile (96 x 192 -> padded 200), coalesced
  for (int it = 0; it < 9; ++it) {
    int c = t + 256 * it;
    int row = c / 24, seg = c - row * 24;
    int col0 = jbase + seg * 8; if (col0 < 0) col0 = 0;
    *(half8*)(vbuf + row * 200 + seg * 8) =
        *(const half8*)(vT + (size_t)row * 4096 + col0);
  }
  __syncthreads();

  // S = Q K^T  (hi*hi + lo*hi + hi*lo)
  f32x4 s[2][12];
#pragma unroll
  for (int m = 0; m < 2; ++m)
#pragma unroll
    for (int n = 0; n < 12; ++n)
      s[m][n] = (f32x4){0.f, 0.f, 0.f, 0.f};

  __builtin_amdgcn_s_setprio(1);
#pragma unroll
  for (int n = 0; n < 12; ++n) {
    if (n < nlo || n >= nlo + 10) continue;
    int krow = n * 16 + fr;
#pragma unroll
    for (int kc = 0; kc < 3; ++kc) {
      half8 b_h = *(const half8*)(kbuf + krow * 104 + kc * 32 + kg * 8);
      half8 b_l = *(const half8*)(klbuf + krow * 104 + kc * 32 + kg * 8);
      s[0][n] = MFMA16(a_h[0][kc], b_h, s[0][n]);
      s[1][n] = MFMA16(a_h[1][kc], b_h, s[1][n]);
      s[0][n] = MFMA16(a_l[0][kc], b_h, s[0][n]);
      s[1][n] = MFMA16(a_l[1][kc], b_h, s[1][n]);
      s[0][n] = MFMA16(a_h[0][kc], b_l, s[0][n]);
      s[1][n] = MFMA16(a_h[1][kc], b_l, s[1][n]);
    }
  }
  __builtin_amdgcn_s_setprio(0);

  // mask + scale + softmax
  const int jmin = (i0 < 128) ? (128 - i0) : 0;
  const float scale = 9.79795897113271f;
  float mx[2][4], sm[2][4], inv[2][4];
#pragma unroll
  for (int m = 0; m < 2; ++m)
#pragma unroll
    for (int r = 0; r < 4; ++r) mx[m][r] = -1e30f;

#pragma unroll
  for (int m = 0; m < 2; ++m)
#pragma unroll
    for (int n = 0; n < 12; ++n) {
      if (n < nlo || n >= nlo + 10) continue;
      int jloc = n * 16 + fr;
#pragma unroll
      for (int r = 0; r < 4; ++r) {
        int iloc = q0 + m * 16 + kg * 4 + r;
        bool valid = (jloc > iloc) && (jloc <= iloc + 128) && (jloc >= jmin);
        float v = valid ? s[m][n][r] * scale : -1e30f;
        s[m][n][r] = v;
        mx[m][r] = fmaxf(mx[m][r], v);
      }
    }
#pragma unroll
  for (int m = 0; m < 2; ++m)
#pragma unroll
    for (int r = 0; r < 4; ++r) {
      float v = mx[m][r];
      v = fmaxf(v, __shfl_xor(v, 1));
      v = fmaxf(v, __shfl_xor(v, 2));
      v = fmaxf(v, __shfl_xor(v, 4));
      v = fmaxf(v, __shfl_xor(v, 8));
      mx[m][r] = v;
      sm[m][r] = 0.f;
    }
#pragma unroll
  for (int m = 0; m < 2; ++m)
#pragma unroll
    for (int n = 0; n < 12; ++n) {
      if (n < nlo || n >= nlo + 10) continue;
#pragma unroll
      for (int r = 0; r < 4; ++r) {
        float p = __expf(s[m][n][r] - mx[m][r]);
        s[m][n][r] = p;
        sm[m][r] += p;
      }
    }
#pragma unroll
  for (int m = 0; m < 2; ++m)
#pragma unroll
    for (int r = 0; r < 4; ++r) {
      float v = sm[m][r];
      v += __shfl_xor(v, 1);
      v += __shfl_xor(v, 2);
      v += __shfl_xor(v, 4);
      v += __shfl_xor(v, 8);
      inv[m][r] = 1.f / v;
    }

  // PV over live key-chunks (pbuf wave-private: same-wave DS ordering, no barriers)
  f16* pw = pbuf[w];
  const int c6lo = nlo >> 1;           // 5 of 6 chunks live
  f32x4 o[2][6];
#pragma unroll
  for (int m = 0; m < 2; ++m)
#pragma unroll
    for (int dn = 0; dn < 6; ++dn)
      o[m][dn] = (f32x4){0.f, 0.f, 0.f, 0.f};

#pragma unroll
  for (int c6 = 0; c6 < 6; ++c6) {
    if (c6 < c6lo || c6 >= c6lo + 5) continue;
#pragma unroll
    for (int m = 0; m < 2; ++m)
#pragma unroll
      for (int nn = 0; nn < 2; ++nn)
#pragma unroll
        for (int r = 0; r < 4; ++r)
          pw[(m * 16 + kg * 4 + r) * 40 + nn * 16 + fr] = (f16)s[m][2 * c6 + nn][r];
    half8 ap0 = *(half8*)(pw + fr * 40 + kg * 8);
    half8 ap1 = *(half8*)(pw + (16 + fr) * 40 + kg * 8);
    __builtin_amdgcn_s_setprio(1);
#pragma unroll
    for (int dn = 0; dn < 6; ++dn) {
      half8 bv = *(half8*)(vbuf + (dn * 16 + fr) * 200 + c6 * 32 + kg * 8);
      o[0][dn] = MFMA16(ap0, bv, o[0][dn]);
      o[1][dn] = MFMA16(ap1, bv, o[1][dn]);
    }
    __builtin_amdgcn_s_setprio(0);
  }

#pragma unroll
  for (int m = 0; m < 2; ++m)
#pragma unroll
    for (int dn = 0; dn < 6; ++dn) {
      int col = h * QD + dn * 16 + fr;
#pragma unroll
      for (int r = 0; r < 4; ++r) {
        int row = i0 + q0 + m * 16 + kg * 4 + r;
        aout[(size_t)row * DM + col] = (f16)(o[m][dn][r] * inv[m][r]);
      }
    }
}

// ---------------------------------------------------------------------------
extern "C" void kernel_launch(void* const* d_in, const int* in_sizes, int n_in,
                              void* d_out, int out_size, void* d_ws, size_t ws_size,
                              hipStream_t stream) {
  const float* x    = (const float*)d_in[0];
  const float* Wqkv = (const float*)d_in[1];
  const float* bqkv = (const float*)d_in[2];
  const float* Wout = (const float*)d_in[3];
  const float* bout = (const float*)d_in[4];
  float* out = (float*)d_out;

  char* ws = (char*)d_ws;
  f16*   xh   = (f16*)(ws);                    // 6291456
  f16*   w1h  = (f16*)(ws + 6291456);          // 1572864
  f16*   w2h  = (f16*)(ws + 7864320);          // 1179648
  float* b1p  = (float*)(ws + 9043968);        // 4096
  float* ctab = (float*)(ws + 9048064);        // 786432
  float* stab = (float*)(ws + 9834496);        // 786432
  f16*   qh   = (f16*)(ws + 10620928);         // 6291456
  f16*   ql   = (f16*)(ws + 16912384);         // 6291456
  f16*   kh   = (f16*)(ws + 23203840);         // 786432
  f16*   kl   = (f16*)(ws + 23990272);         // 786432
  f16*   vT   = (f16*)(ws + 24776704);         // 786432
  f16*   aout = (f16*)(ws + 25563136);         // 6291456 -> total 31854592

  prep_kernel<<<dim3(5444), dim3(256), 0, stream>>>(x, Wqkv, bqkv, Wout,
                                                    xh, w1h, w2h, b1p, ctab, stab);
  gemm_qkv_rope<<<dim3(128, 8), dim3(256), 0, stream>>>(xh, w1h, b1p, ctab, stab,
                                                        qh, ql, kh, kl, vT);
  attn2_kernel<<<dim3(64, 4), dim3(256), 0, stream>>>(qh, ql, kh, kl, vT, aout);
  gemm_f16_tn<<<dim3(128, 6), dim3(256), 0, stream>>>(aout, w2h, bout, out, 768, 768);
}